// Round 1
// baseline (345.180 us; speedup 1.0000x reference)
//
#include <hip/hip_runtime.h>

// ---------------------------------------------------------------------------
// GCN 2-layer forward on MI355X.
// Pipeline:
//   memset(deg,cursor)=0
//   k_degree:   deg[dst]++ over 640k edges (int atomics)
//   k_dinv:     dinv[i] = rsqrt(deg[i]+1)          (+1 = self loop)
//   k_scan:     rowptr = exclusive_scan(deg)        (CSR by dst)
//   k_fill:     col[rowptr[dst]+pos++] = src
//   k_pack_w1/w2: W -> MFMA-fragment-packed f16 (B operand), W2 padded to 48
//   k_pack_x:   x fp32 -> f16 packed in MFMA A-fragment order
//   k_gemm<..>: h1 = x @ W1           (f16 MFMA, LDS-free, packed operands)
//   k_agg1:     hrelu = relu(Ahat*h1 + b1)          (wave per node, f16 rows)
//   k_pack_h:   hrelu -> packed A for GEMM2
//   k_gemm<..>: g = hrelu @ W2  (48 cols, col47 zero-padded)
//   k_agg2:     out = log_softmax(Ahat*g + b2)      (fused shuffle reduce)
// ---------------------------------------------------------------------------

typedef _Float16 f16;
typedef _Float16 f16x8 __attribute__((ext_vector_type(8)));
typedef _Float16 f16x4 __attribute__((ext_vector_type(4)));
typedef float f32x4 __attribute__((ext_vector_type(4)));

#define N_NODES 40000
#define N_EDGES 640000
#define D_IN 512
#define D_HID 256
#define D_OUT 47
#define D_OUT_PAD 48

// ---------------- CSR build ----------------

__global__ void k_degree(const int* __restrict__ eidx, int* __restrict__ deg) {
    int e = blockIdx.x * blockDim.x + threadIdx.x;
    if (e < N_EDGES) {
        int d = eidx[N_EDGES + e];  // dst
        atomicAdd(&deg[d], 1);
    }
}

__global__ void k_dinv(const int* __restrict__ deg, float* __restrict__ dinv) {
    int i = blockIdx.x * blockDim.x + threadIdx.x;
    if (i < N_NODES) dinv[i] = rsqrtf((float)(deg[i] + 1));
}

__global__ void k_scan(const int* __restrict__ deg, int* __restrict__ rowptr) {
    __shared__ int partial[1024];
    __shared__ int offs[1025];
    const int S = 40;  // 1024*40 = 40960 >= 40000
    int t = threadIdx.x;
    int base = t * S;
    int s = 0;
    for (int i = 0; i < S; ++i) {
        int idx = base + i;
        if (idx < N_NODES) s += deg[idx];
    }
    partial[t] = s;
    __syncthreads();
    if (t == 0) {
        int acc = 0;
        for (int i = 0; i < 1024; ++i) { offs[i] = acc; acc += partial[i]; }
        offs[1024] = acc;
    }
    __syncthreads();
    int acc = offs[t];
    for (int i = 0; i < S; ++i) {
        int idx = base + i;
        if (idx < N_NODES) { rowptr[idx] = acc; acc += deg[idx]; }
    }
    if (t == 1023) rowptr[N_NODES] = offs[1024];
}

__global__ void k_fill(const int* __restrict__ eidx, const int* __restrict__ rowptr,
                       int* __restrict__ cursor, int* __restrict__ col) {
    int e = blockIdx.x * blockDim.x + threadIdx.x;
    if (e < N_EDGES) {
        int s = eidx[e];
        int d = eidx[N_EDGES + e];
        int pos = atomicAdd(&cursor[d], 1);
        col[rowptr[d] + pos] = s;
    }
}

// ---------------- operand packing ----------------
// A-fragment packing (mfma_f32_16x16x32_f16):
//   lane l holds A[row = 16-blk + (l&15)][k = kt*32 + (l>>4)*8 + j], j=0..7
//   packed at ((m16*KT + kt)*64 + l)*8 + j
// B-fragment packing:
//   lane l holds B[k = kt*32 + (l>>4)*8 + j][col = nf*16 + (l&15)]
//   packed at ((kt*NFB + nf)*64 + l)*8 + j

__global__ void k_pack_w1(const float* __restrict__ W, f16* __restrict__ Wp) {
    // KT=16, NFB=16 : units = 16*16*64 = 16384
    int u = blockIdx.x * blockDim.x + threadIdx.x;
    if (u >= 16 * 16 * 64) return;
    int l = u & 63;
    int nf = (u >> 6) & 15;
    int kt = u >> 10;
    int k0 = kt * 32 + (l >> 4) * 8;
    int c = nf * 16 + (l & 15);
    f16x8 o;
#pragma unroll
    for (int j = 0; j < 8; ++j) o[j] = (f16)W[(size_t)(k0 + j) * D_HID + c];
    *(f16x8*)(Wp + (size_t)u * 8) = o;
}

__global__ void k_pack_w2(const float* __restrict__ W, f16* __restrict__ Wp) {
    // KT=8, NFB=3 : units = 8*3*64 = 1536
    int u = blockIdx.x * blockDim.x + threadIdx.x;
    if (u >= 8 * 3 * 64) return;
    int l = u & 63;
    int nf = (u / 64) % 3;
    int kt = u / 192;
    int k0 = kt * 32 + (l >> 4) * 8;
    int c = nf * 16 + (l & 15);
    f16x8 o;
#pragma unroll
    for (int j = 0; j < 8; ++j)
        o[j] = (c < D_OUT) ? (f16)W[(size_t)(k0 + j) * D_OUT + c] : (f16)0.0f;
    *(f16x8*)(Wp + (size_t)u * 8) = o;
}

__global__ void k_pack_x(const float* __restrict__ x, f16* __restrict__ xp) {
    // KT=16 : units = 2500 * 16 * 64 = 2,560,000 ; grid 10000x256 exact
    int u = blockIdx.x * blockDim.x + threadIdx.x;
    int l = u & 63;
    int kt = (u >> 6) & 15;
    int m16 = u >> 10;
    int row = m16 * 16 + (l & 15);
    int k0 = kt * 32 + (l >> 4) * 8;
    const float4* p = (const float4*)(x + (size_t)row * D_IN + k0);
    float4 lo = p[0], hi = p[1];
    f16x8 o;
    o[0] = (f16)lo.x; o[1] = (f16)lo.y; o[2] = (f16)lo.z; o[3] = (f16)lo.w;
    o[4] = (f16)hi.x; o[5] = (f16)hi.y; o[6] = (f16)hi.z; o[7] = (f16)hi.w;
    *(f16x8*)(xp + (size_t)u * 8) = o;
}

__global__ void k_pack_h(const f16* __restrict__ h, f16* __restrict__ hp) {
    // KT=8 : units = 2500 * 8 * 64 = 1,280,000 ; grid 5000x256 exact
    int u = blockIdx.x * blockDim.x + threadIdx.x;
    int l = u & 63;
    int kt = (u >> 6) & 7;
    int m16 = u >> 9;
    int row = m16 * 16 + (l & 15);
    int k0 = kt * 32 + (l >> 4) * 8;
    f16x8 v = *(const f16x8*)(h + (size_t)row * D_HID + k0);
    *(f16x8*)(hp + (size_t)u * 8) = v;
}

// ---------------- GEMM (LDS-free, packed operands) ----------------
// Wave computes 64 rows x (WNF*16) cols. Block = 4 waves.
// GEMM1: KT=16, NFB=16, WNF=4, WROWS=1, WCOLS=4, LDC=256 (block = 64r x 256c)
// GEMM2: KT=8,  NFB=3,  WNF=3, WROWS=4, WCOLS=1, LDC=48  (block = 256r x 48c)

template <int KT, int NFB, int WNF, int WROWS, int WCOLS, int LDC>
__global__ __launch_bounds__(256) void k_gemm(const f16* __restrict__ Ap,
                                              const f16* __restrict__ Bp,
                                              f16* __restrict__ C, int M) {
    int wid = threadIdx.x >> 6;
    int lane = threadIdx.x & 63;
    int rowTile = blockIdx.x * WROWS + wid / WCOLS;
    int rowBase = rowTile * 64;
    if (rowBase >= M) return;
    int nf0 = (wid % WCOLS) * WNF;

    f32x4 acc[4][WNF];
#pragma unroll
    for (int mi = 0; mi < 4; ++mi)
#pragma unroll
        for (int ni = 0; ni < WNF; ++ni) acc[mi][ni] = (f32x4)(0.0f);

    int m16b = rowTile * 4;
    for (int kt = 0; kt < KT; ++kt) {
        f16x8 a[4], b[WNF];
#pragma unroll
        for (int mi = 0; mi < 4; ++mi)
            a[mi] = *(const f16x8*)(Ap + ((size_t)((m16b + mi) * KT + kt) * 64 + lane) * 8);
#pragma unroll
        for (int ni = 0; ni < WNF; ++ni)
            b[ni] = *(const f16x8*)(Bp + ((size_t)(kt * NFB + nf0 + ni) * 64 + lane) * 8);
#pragma unroll
        for (int mi = 0; mi < 4; ++mi)
#pragma unroll
            for (int ni = 0; ni < WNF; ++ni)
                acc[mi][ni] = __builtin_amdgcn_mfma_f32_16x16x32_f16(a[mi], b[ni], acc[mi][ni], 0, 0, 0);
    }

    int r0 = (lane >> 4) * 4;
    int c0 = lane & 15;
#pragma unroll
    for (int mi = 0; mi < 4; ++mi)
#pragma unroll
        for (int ni = 0; ni < WNF; ++ni)
#pragma unroll
            for (int r = 0; r < 4; ++r) {
                int row = rowBase + mi * 16 + r0 + r;
                C[(size_t)row * LDC + (nf0 + ni) * 16 + c0] = (f16)acc[mi][ni][r];
            }
}

// ---------------- aggregation ----------------

__global__ __launch_bounds__(256) void k_agg1(const f16* __restrict__ h1,
                                              const int* __restrict__ rowptr,
                                              const int* __restrict__ col,
                                              const float* __restrict__ dinv,
                                              const float* __restrict__ b1,
                                              f16* __restrict__ hrelu) {
    int node = blockIdx.x * 4 + (threadIdx.x >> 6);
    int lane = threadIdx.x & 63;
    float di = dinv[node];
    float w_self = di * di;
    f16x4 v = *(const f16x4*)(h1 + (size_t)node * D_HID + lane * 4);
    float a0 = (float)v[0] * w_self, a1 = (float)v[1] * w_self;
    float a2 = (float)v[2] * w_self, a3 = (float)v[3] * w_self;
    int e0 = rowptr[node], e1 = rowptr[node + 1];
    for (int e = e0; e < e1; ++e) {
        int s = col[e];
        float w = dinv[s] * di;
        f16x4 u = *(const f16x4*)(h1 + (size_t)s * D_HID + lane * 4);
        a0 += (float)u[0] * w; a1 += (float)u[1] * w;
        a2 += (float)u[2] * w; a3 += (float)u[3] * w;
    }
    float4 bv = *(const float4*)(b1 + lane * 4);
    f16x4 o;
    o[0] = (f16)fmaxf(a0 + bv.x, 0.0f);
    o[1] = (f16)fmaxf(a1 + bv.y, 0.0f);
    o[2] = (f16)fmaxf(a2 + bv.z, 0.0f);
    o[3] = (f16)fmaxf(a3 + bv.w, 0.0f);
    *(f16x4*)(hrelu + (size_t)node * D_HID + lane * 4) = o;
}

__global__ __launch_bounds__(256) void k_agg2(const f16* __restrict__ g,
                                              const int* __restrict__ rowptr,
                                              const int* __restrict__ col,
                                              const float* __restrict__ dinv,
                                              const float* __restrict__ b2,
                                              float* __restrict__ out) {
    int node = blockIdx.x * 4 + (threadIdx.x >> 6);
    int lane = threadIdx.x & 63;
    float di = dinv[node];
    float acc = 0.0f;
    if (lane < D_OUT_PAD) acc = (float)g[(size_t)node * D_OUT_PAD + lane] * di * di;
    int e0 = rowptr[node], e1 = rowptr[node + 1];
    for (int e = e0; e < e1; ++e) {
        int s = col[e];
        float w = dinv[s] * di;
        if (lane < D_OUT_PAD) acc += (float)g[(size_t)s * D_OUT_PAD + lane] * w;
    }
    float z = (lane < D_OUT) ? acc + b2[lane] : -3.0e38f;
    // wave max
    float mx = z;
#pragma unroll
    for (int off = 32; off >= 1; off >>= 1) mx = fmaxf(mx, __shfl_xor(mx, off));
    float ex = (lane < D_OUT) ? expf(z - mx) : 0.0f;
    float sum = ex;
#pragma unroll
    for (int off = 32; off >= 1; off >>= 1) sum += __shfl_xor(sum, off);
    if (lane < D_OUT) out[(size_t)node * D_OUT + lane] = z - mx - logf(sum);
}

// ---------------- launcher ----------------

extern "C" void kernel_launch(void* const* d_in, const int* in_sizes, int n_in,
                              void* d_out, int out_size, void* d_ws, size_t ws_size,
                              hipStream_t stream) {
    const float* x  = (const float*)d_in[0];
    const int*   ei = (const int*)d_in[1];   // [2][640000], harness int32
    const float* W1 = (const float*)d_in[2];
    const float* b1 = (const float*)d_in[3];
    const float* W2 = (const float*)d_in[4];
    const float* b2 = (const float*)d_in[5];
    float* out = (float*)d_out;

    char* ws = (char*)d_ws;
    int*   degi   = (int*)(ws + 0);              // 160000
    int*   cursor = (int*)(ws + 160000);         // 160000
    float* dinv   = (float*)(ws + 320000);       // 160000
    int*   rowptr = (int*)(ws + 480000);         // 160256 (40001 ints)
    int*   col    = (int*)(ws + 640256);         // 2,560,000
    f16*   w1p    = (f16*)(ws + 3200256);        // 262,144
    f16*   w2p    = (f16*)(ws + 3462400);        // 24,576
    char*  bufA   = ws + 3486976;                // 40,960,000 (xp -> hrelu,g)
    char*  bufB   = ws + 44446976;               // 20,480,000 (h1 -> hp)
    f16* xp    = (f16*)bufA;
    f16* hrelu = (f16*)bufA;                        // reuses xp after GEMM1
    f16* g     = (f16*)(bufA + 20480000);
    f16* h1    = (f16*)bufB;
    f16* hp    = (f16*)bufB;                        // reuses h1 after agg1

    hipMemsetAsync(d_ws, 0, 320000, stream);  // degi + cursor

    k_degree<<<2500, 256, 0, stream>>>(ei, degi);
    k_dinv<<<157, 256, 0, stream>>>(degi, dinv);
    k_scan<<<1, 1024, 0, stream>>>(degi, rowptr);
    k_fill<<<2500, 256, 0, stream>>>(ei, rowptr, cursor, col);

    k_pack_w1<<<64, 256, 0, stream>>>(W1, w1p);
    k_pack_w2<<<6, 256, 0, stream>>>(W2, w2p);
    k_pack_x<<<10000, 256, 0, stream>>>(x, xp);

    k_gemm<16, 16, 4, 1, 4, 256><<<625, 256, 0, stream>>>(xp, w1p, h1, N_NODES);
    k_agg1<<<10000, 256, 0, stream>>>(h1, rowptr, col, dinv, b1, hrelu);
    k_pack_h<<<5000, 256, 0, stream>>>(hrelu, hp);
    k_gemm<8, 3, 3, 4, 1, D_OUT_PAD><<<157, 256, 0, stream>>>(hp, w2p, g, N_NODES);
    k_agg2<<<10000, 256, 0, stream>>>(g, rowptr, col, dinv, b2, out);
}

// Round 2
// 281.740 us; speedup vs baseline: 1.2252x; 1.2252x over previous
//
#include <hip/hip_runtime.h>

// ---------------------------------------------------------------------------
// GCN 2-layer forward on MI355X.
// Pipeline:
//   memset(deg,cursor)=0
//   k_degree:   deg[dst]++ over 640k edges (int atomics)
//   k_scan:     rowptr = exclusive_scan(deg) (parallel), fused dinv=rsqrt(deg+1)
//   k_fill:     col[rowptr[dst]+pos++] = src
//   k_pack_w1/w2: W -> MFMA-fragment-packed f16 (B operand), W2 padded to 48
//   k_pack_x:   x fp32 -> f16 packed in MFMA A-fragment order
//   k_gemm<..>: h1 = x @ W1           (f16 MFMA, LDS-free, packed operands)
//   k_agg1:     hrelu = relu(Ahat*h1 + b1)          (wave per node, f16 rows)
//   k_pack_h:   hrelu -> packed A for GEMM2
//   k_gemm<..>: g = hrelu @ W2  (48 cols, col47 zero-padded)
//   k_agg2:     out = log_softmax(Ahat*g + b2)      (fused shuffle reduce)
// ---------------------------------------------------------------------------

typedef _Float16 f16;
typedef _Float16 f16x8 __attribute__((ext_vector_type(8)));
typedef _Float16 f16x4 __attribute__((ext_vector_type(4)));
typedef float f32x4 __attribute__((ext_vector_type(4)));

#define N_NODES 40000
#define N_EDGES 640000
#define D_IN 512
#define D_HID 256
#define D_OUT 47
#define D_OUT_PAD 48

// ---------------- CSR build ----------------

__global__ void k_degree(const int* __restrict__ eidx, int* __restrict__ deg) {
    int e = blockIdx.x * blockDim.x + threadIdx.x;
    if (e < N_EDGES) {
        int d = eidx[N_EDGES + e];  // dst
        atomicAdd(&deg[d], 1);
    }
}

// Parallel single-block scan: 1024 threads x 40 elems. 40000 = 1000*40 exactly.
// Also emits dinv[i] = rsqrt(deg[i]+1)  (+1 = self loop).
__global__ __launch_bounds__(1024) void k_scan(const int* __restrict__ deg,
                                               int* __restrict__ rowptr,
                                               float* __restrict__ dinv) {
    __shared__ int wsum[16];
    const int S = 40;
    int t = threadIdx.x;
    int lane = t & 63;
    int wid = t >> 6;
    int base = t * S;
    bool live = (base < N_NODES);  // threads 1000..1023 idle (loads only)

    int v[S];
    int tot = 0;
#pragma unroll
    for (int i = 0; i < S / 4; ++i) {
        int4 q = make_int4(0, 0, 0, 0);
        if (live) q = *(const int4*)(deg + base + i * 4);
        v[i * 4 + 0] = q.x; v[i * 4 + 1] = q.y;
        v[i * 4 + 2] = q.z; v[i * 4 + 3] = q.w;
        tot += q.x + q.y + q.z + q.w;
    }

    // inclusive 64-lane scan of tot
    int inc = tot;
#pragma unroll
    for (int off = 1; off < 64; off <<= 1) {
        int n = __shfl_up(inc, off);
        if (lane >= off) inc += n;
    }
    if (lane == 63) wsum[wid] = inc;  // wave total
    __syncthreads();
    if (t < 16) {
        int wv = wsum[t];
        int winc = wv;
#pragma unroll
        for (int off = 1; off < 16; off <<= 1) {
            int n = __shfl_up(winc, off);
            if (t >= off) winc += n;
        }
        wsum[t] = winc - wv;  // exclusive wave offset
    }
    __syncthreads();

    int acc = wsum[wid] + (inc - tot);  // exclusive offset for this thread
#pragma unroll
    for (int i = 0; i < S / 4; ++i) {
        int4 r; float4 f;
        r.x = acc; f.x = rsqrtf((float)(v[i * 4 + 0] + 1)); acc += v[i * 4 + 0];
        r.y = acc; f.y = rsqrtf((float)(v[i * 4 + 1] + 1)); acc += v[i * 4 + 1];
        r.z = acc; f.z = rsqrtf((float)(v[i * 4 + 2] + 1)); acc += v[i * 4 + 2];
        r.w = acc; f.w = rsqrtf((float)(v[i * 4 + 3] + 1)); acc += v[i * 4 + 3];
        if (live) {
            *(int4*)(rowptr + base + i * 4) = r;
            *(float4*)(dinv + base + i * 4) = f;
        }
    }
    if (t == 0) rowptr[N_NODES] = N_EDGES;  // sum(deg) == E statically
}

__global__ void k_fill(const int* __restrict__ eidx, const int* __restrict__ rowptr,
                       int* __restrict__ cursor, int* __restrict__ col) {
    int e = blockIdx.x * blockDim.x + threadIdx.x;
    if (e < N_EDGES) {
        int s = eidx[e];
        int d = eidx[N_EDGES + e];
        int pos = atomicAdd(&cursor[d], 1);
        col[rowptr[d] + pos] = s;
    }
}

// ---------------- operand packing ----------------
// A-fragment packing (mfma_f32_16x16x32_f16):
//   lane l holds A[row = 16-blk + (l&15)][k = kt*32 + (l>>4)*8 + j], j=0..7
//   packed at ((m16*KT + kt)*64 + l)*8 + j
// B-fragment packing:
//   lane l holds B[k = kt*32 + (l>>4)*8 + j][col = nf*16 + (l&15)]
//   packed at ((kt*NFB + nf)*64 + l)*8 + j

__global__ void k_pack_w1(const float* __restrict__ W, f16* __restrict__ Wp) {
    // KT=16, NFB=16 : units = 16*16*64 = 16384
    int u = blockIdx.x * blockDim.x + threadIdx.x;
    if (u >= 16 * 16 * 64) return;
    int l = u & 63;
    int nf = (u >> 6) & 15;
    int kt = u >> 10;
    int k0 = kt * 32 + (l >> 4) * 8;
    int c = nf * 16 + (l & 15);
    f16x8 o;
#pragma unroll
    for (int j = 0; j < 8; ++j) o[j] = (f16)W[(size_t)(k0 + j) * D_HID + c];
    *(f16x8*)(Wp + (size_t)u * 8) = o;
}

__global__ void k_pack_w2(const float* __restrict__ W, f16* __restrict__ Wp) {
    // KT=8, NFB=3 : units = 8*3*64 = 1536
    int u = blockIdx.x * blockDim.x + threadIdx.x;
    if (u >= 8 * 3 * 64) return;
    int l = u & 63;
    int nf = (u / 64) % 3;
    int kt = u / 192;
    int k0 = kt * 32 + (l >> 4) * 8;
    int c = nf * 16 + (l & 15);
    f16x8 o;
#pragma unroll
    for (int j = 0; j < 8; ++j)
        o[j] = (c < D_OUT) ? (f16)W[(size_t)(k0 + j) * D_OUT + c] : (f16)0.0f;
    *(f16x8*)(Wp + (size_t)u * 8) = o;
}

__global__ void k_pack_x(const float* __restrict__ x, f16* __restrict__ xp) {
    // KT=16 : units = 2500 * 16 * 64 = 2,560,000 ; grid 10000x256 exact
    int u = blockIdx.x * blockDim.x + threadIdx.x;
    int l = u & 63;
    int kt = (u >> 6) & 15;
    int m16 = u >> 10;
    int row = m16 * 16 + (l & 15);
    int k0 = kt * 32 + (l >> 4) * 8;
    const float4* p = (const float4*)(x + (size_t)row * D_IN + k0);
    float4 lo = p[0], hi = p[1];
    f16x8 o;
    o[0] = (f16)lo.x; o[1] = (f16)lo.y; o[2] = (f16)lo.z; o[3] = (f16)lo.w;
    o[4] = (f16)hi.x; o[5] = (f16)hi.y; o[6] = (f16)hi.z; o[7] = (f16)hi.w;
    *(f16x8*)(xp + (size_t)u * 8) = o;
}

__global__ void k_pack_h(const f16* __restrict__ h, f16* __restrict__ hp) {
    // KT=8 : units = 2500 * 8 * 64 = 1,280,000 ; grid 5000x256 exact
    int u = blockIdx.x * blockDim.x + threadIdx.x;
    int l = u & 63;
    int kt = (u >> 6) & 7;
    int m16 = u >> 9;
    int row = m16 * 16 + (l & 15);
    int k0 = kt * 32 + (l >> 4) * 8;
    f16x8 v = *(const f16x8*)(h + (size_t)row * D_HID + k0);
    *(f16x8*)(hp + (size_t)u * 8) = v;
}

// ---------------- GEMM (LDS-free, packed operands) ----------------
// Wave computes 64 rows x (WNF*16) cols. Block = 4 waves.
// GEMM1: KT=16, NFB=16, WNF=4, WROWS=1, WCOLS=4, LDC=256 (block = 64r x 256c)
// GEMM2: KT=8,  NFB=3,  WNF=3, WROWS=4, WCOLS=1, LDC=48  (block = 256r x 48c)

template <int KT, int NFB, int WNF, int WROWS, int WCOLS, int LDC>
__global__ __launch_bounds__(256) void k_gemm(const f16* __restrict__ Ap,
                                              const f16* __restrict__ Bp,
                                              f16* __restrict__ C, int M) {
    int wid = threadIdx.x >> 6;
    int lane = threadIdx.x & 63;
    int rowTile = blockIdx.x * WROWS + wid / WCOLS;
    int rowBase = rowTile * 64;
    if (rowBase >= M) return;
    int nf0 = (wid % WCOLS) * WNF;

    f32x4 acc[4][WNF];
#pragma unroll
    for (int mi = 0; mi < 4; ++mi)
#pragma unroll
        for (int ni = 0; ni < WNF; ++ni) acc[mi][ni] = (f32x4)(0.0f);

    int m16b = rowTile * 4;
    for (int kt = 0; kt < KT; ++kt) {
        f16x8 a[4], b[WNF];
#pragma unroll
        for (int mi = 0; mi < 4; ++mi)
            a[mi] = *(const f16x8*)(Ap + ((size_t)((m16b + mi) * KT + kt) * 64 + lane) * 8);
#pragma unroll
        for (int ni = 0; ni < WNF; ++ni)
            b[ni] = *(const f16x8*)(Bp + ((size_t)(kt * NFB + nf0 + ni) * 64 + lane) * 8);
#pragma unroll
        for (int mi = 0; mi < 4; ++mi)
#pragma unroll
            for (int ni = 0; ni < WNF; ++ni)
                acc[mi][ni] = __builtin_amdgcn_mfma_f32_16x16x32_f16(a[mi], b[ni], acc[mi][ni], 0, 0, 0);
    }

    int r0 = (lane >> 4) * 4;
    int c0 = lane & 15;
#pragma unroll
    for (int mi = 0; mi < 4; ++mi)
#pragma unroll
        for (int ni = 0; ni < WNF; ++ni)
#pragma unroll
            for (int r = 0; r < 4; ++r) {
                int row = rowBase + mi * 16 + r0 + r;
                C[(size_t)row * LDC + (nf0 + ni) * 16 + c0] = (f16)acc[mi][ni][r];
            }
}

// ---------------- aggregation ----------------

__global__ __launch_bounds__(256) void k_agg1(const f16* __restrict__ h1,
                                              const int* __restrict__ rowptr,
                                              const int* __restrict__ col,
                                              const float* __restrict__ dinv,
                                              const float* __restrict__ b1,
                                              f16* __restrict__ hrelu) {
    int node = blockIdx.x * 4 + (threadIdx.x >> 6);
    int lane = threadIdx.x & 63;
    float di = dinv[node];
    float w_self = di * di;
    f16x4 v = *(const f16x4*)(h1 + (size_t)node * D_HID + lane * 4);
    float a0 = (float)v[0] * w_self, a1 = (float)v[1] * w_self;
    float a2 = (float)v[2] * w_self, a3 = (float)v[3] * w_self;
    int e0 = rowptr[node], e1 = rowptr[node + 1];
    for (int e = e0; e < e1; ++e) {
        int s = col[e];
        float w = dinv[s] * di;
        f16x4 u = *(const f16x4*)(h1 + (size_t)s * D_HID + lane * 4);
        a0 += (float)u[0] * w; a1 += (float)u[1] * w;
        a2 += (float)u[2] * w; a3 += (float)u[3] * w;
    }
    float4 bv = *(const float4*)(b1 + lane * 4);
    f16x4 o;
    o[0] = (f16)fmaxf(a0 + bv.x, 0.0f);
    o[1] = (f16)fmaxf(a1 + bv.y, 0.0f);
    o[2] = (f16)fmaxf(a2 + bv.z, 0.0f);
    o[3] = (f16)fmaxf(a3 + bv.w, 0.0f);
    *(f16x4*)(hrelu + (size_t)node * D_HID + lane * 4) = o;
}

__global__ __launch_bounds__(256) void k_agg2(const f16* __restrict__ g,
                                              const int* __restrict__ rowptr,
                                              const int* __restrict__ col,
                                              const float* __restrict__ dinv,
                                              const float* __restrict__ b2,
                                              float* __restrict__ out) {
    int node = blockIdx.x * 4 + (threadIdx.x >> 6);
    int lane = threadIdx.x & 63;
    float di = dinv[node];
    float acc = 0.0f;
    if (lane < D_OUT_PAD) acc = (float)g[(size_t)node * D_OUT_PAD + lane] * di * di;
    int e0 = rowptr[node], e1 = rowptr[node + 1];
    for (int e = e0; e < e1; ++e) {
        int s = col[e];
        float w = dinv[s] * di;
        if (lane < D_OUT_PAD) acc += (float)g[(size_t)s * D_OUT_PAD + lane] * w;
    }
    float z = (lane < D_OUT) ? acc + b2[lane] : -3.0e38f;
    // wave max
    float mx = z;
#pragma unroll
    for (int off = 32; off >= 1; off >>= 1) mx = fmaxf(mx, __shfl_xor(mx, off));
    float ex = (lane < D_OUT) ? expf(z - mx) : 0.0f;
    float sum = ex;
#pragma unroll
    for (int off = 32; off >= 1; off >>= 1) sum += __shfl_xor(sum, off);
    if (lane < D_OUT) out[(size_t)node * D_OUT + lane] = z - mx - logf(sum);
}

// ---------------- launcher ----------------

extern "C" void kernel_launch(void* const* d_in, const int* in_sizes, int n_in,
                              void* d_out, int out_size, void* d_ws, size_t ws_size,
                              hipStream_t stream) {
    const float* x  = (const float*)d_in[0];
    const int*   ei = (const int*)d_in[1];   // [2][640000], harness int32
    const float* W1 = (const float*)d_in[2];
    const float* b1 = (const float*)d_in[3];
    const float* W2 = (const float*)d_in[4];
    const float* b2 = (const float*)d_in[5];
    float* out = (float*)d_out;

    char* ws = (char*)d_ws;
    int*   degi   = (int*)(ws + 0);              // 160000
    int*   cursor = (int*)(ws + 160000);         // 160000
    float* dinv   = (float*)(ws + 320000);       // 160000
    int*   rowptr = (int*)(ws + 480000);         // 160256 (40001 ints)
    int*   col    = (int*)(ws + 640256);         // 2,560,000
    f16*   w1p    = (f16*)(ws + 3200256);        // 262,144
    f16*   w2p    = (f16*)(ws + 3462400);        // 24,576
    char*  bufA   = ws + 3486976;                // 40,960,000 (xp -> hrelu,g)
    char*  bufB   = ws + 44446976;               // 20,480,000 (h1 -> hp)
    f16* xp    = (f16*)bufA;
    f16* hrelu = (f16*)bufA;                        // reuses xp after GEMM1
    f16* g     = (f16*)(bufA + 20480000);
    f16* h1    = (f16*)bufB;
    f16* hp    = (f16*)bufB;                        // reuses h1 after agg1

    hipMemsetAsync(d_ws, 0, 320000, stream);  // degi + cursor

    k_degree<<<2500, 256, 0, stream>>>(ei, degi);
    k_scan<<<1, 1024, 0, stream>>>(degi, rowptr, dinv);
    k_fill<<<2500, 256, 0, stream>>>(ei, rowptr, cursor, col);

    k_pack_w1<<<64, 256, 0, stream>>>(W1, w1p);
    k_pack_w2<<<6, 256, 0, stream>>>(W2, w2p);
    k_pack_x<<<10000, 256, 0, stream>>>(x, xp);

    k_gemm<16, 16, 4, 1, 4, 256><<<625, 256, 0, stream>>>(xp, w1p, h1, N_NODES);
    k_agg1<<<10000, 256, 0, stream>>>(h1, rowptr, col, dinv, b1, hrelu);
    k_pack_h<<<5000, 256, 0, stream>>>(hrelu, hp);
    k_gemm<8, 3, 3, 4, 1, D_OUT_PAD><<<157, 256, 0, stream>>>(hp, w2p, g, N_NODES);
    k_agg2<<<10000, 256, 0, stream>>>(g, rowptr, col, dinv, b2, out);
}

// Round 4
// 224.860 us; speedup vs baseline: 1.5351x; 1.2530x over previous
//
#include <hip/hip_runtime.h>

// ---------------------------------------------------------------------------
// GCN 2-layer forward on MI355X.
//   memset(deg,cursor)=0
//   k_degree: deg[dst]++                         (int atomics)
//   k_scan:   rowptr = exscan(deg) + dinv=rsqrt(deg+1)   (parallel, 1 block)
//   k_fill:   col[rowptr[dst]+pos++] = src       (CSR by dst)
//   k_pack_w1/w2: W -> MFMA B-fragment f16 (W2 padded to 48)
//   k_gemm1:  h1 = f16(x) @ W1   (fused f32->f16 A conversion, LDS-free MFMA)
//   k_agg1:   hp = packA(relu(Ahat*h1 + b1))     (MLP gather + fused pack)
//   k_gemm2:  g = hp @ W2  (48 cols, col47 zero)  [grid 157 — covers 40192 rows]
//   k_agg2:   out = log_softmax(Ahat*g + b2)
// ---------------------------------------------------------------------------

typedef _Float16 f16;
typedef _Float16 f16x8 __attribute__((ext_vector_type(8)));
typedef float f32x4 __attribute__((ext_vector_type(4)));

#define N_NODES 40000
#define N_EDGES 640000
#define D_IN 512
#define D_HID 256
#define D_OUT 47
#define D_OUT_PAD 48

// ---------------- CSR build ----------------

__global__ void k_degree(const int* __restrict__ eidx, int* __restrict__ deg) {
    int e = blockIdx.x * blockDim.x + threadIdx.x;
    if (e < N_EDGES) atomicAdd(&deg[eidx[N_EDGES + e]], 1);
}

// Parallel single-block scan: 1024 threads x 40 elems; fused dinv.
__global__ __launch_bounds__(1024) void k_scan(const int* __restrict__ deg,
                                               int* __restrict__ rowptr,
                                               float* __restrict__ dinv) {
    __shared__ int wsum[16];
    const int S = 40;
    int t = threadIdx.x;
    int lane = t & 63;
    int wid = t >> 6;
    int base = t * S;
    bool live = (base < N_NODES);

    int v[S];
    int tot = 0;
#pragma unroll
    for (int i = 0; i < S / 4; ++i) {
        int4 q = make_int4(0, 0, 0, 0);
        if (live) q = *(const int4*)(deg + base + i * 4);
        v[i * 4 + 0] = q.x; v[i * 4 + 1] = q.y;
        v[i * 4 + 2] = q.z; v[i * 4 + 3] = q.w;
        tot += q.x + q.y + q.z + q.w;
    }
    int inc = tot;
#pragma unroll
    for (int off = 1; off < 64; off <<= 1) {
        int n = __shfl_up(inc, off);
        if (lane >= off) inc += n;
    }
    if (lane == 63) wsum[wid] = inc;
    __syncthreads();
    if (t < 16) {
        int wv = wsum[t];
        int winc = wv;
#pragma unroll
        for (int off = 1; off < 16; off <<= 1) {
            int n = __shfl_up(winc, off);
            if (t >= off) winc += n;
        }
        wsum[t] = winc - wv;
    }
    __syncthreads();
    int acc = wsum[wid] + (inc - tot);
#pragma unroll
    for (int i = 0; i < S / 4; ++i) {
        int4 r; float4 f;
        r.x = acc; f.x = rsqrtf((float)(v[i * 4 + 0] + 1)); acc += v[i * 4 + 0];
        r.y = acc; f.y = rsqrtf((float)(v[i * 4 + 1] + 1)); acc += v[i * 4 + 1];
        r.z = acc; f.z = rsqrtf((float)(v[i * 4 + 2] + 1)); acc += v[i * 4 + 2];
        r.w = acc; f.w = rsqrtf((float)(v[i * 4 + 3] + 1)); acc += v[i * 4 + 3];
        if (live) {
            *(int4*)(rowptr + base + i * 4) = r;
            *(float4*)(dinv + base + i * 4) = f;
        }
    }
    if (t == 0) rowptr[N_NODES] = N_EDGES;
}

__global__ void k_fill(const int* __restrict__ eidx, const int* __restrict__ rowptr,
                       int* __restrict__ cursor, int* __restrict__ col) {
    int e = blockIdx.x * blockDim.x + threadIdx.x;
    if (e < N_EDGES) {
        int s = eidx[e];
        int d = eidx[N_EDGES + e];
        int pos = atomicAdd(&cursor[d], 1);
        col[rowptr[d] + pos] = s;
    }
}

// ---------------- weight packing (B-fragment order) ----------------
// lane l holds B[k = kt*32 + (l>>4)*8 + j][col = nf*16 + (l&15)]
// packed at ((kt*NFB + nf)*64 + l)*8 + j

__global__ void k_pack_w1(const float* __restrict__ W, f16* __restrict__ Wp) {
    int u = blockIdx.x * blockDim.x + threadIdx.x;
    if (u >= 16 * 16 * 64) return;
    int l = u & 63;
    int nf = (u >> 6) & 15;
    int kt = u >> 10;
    int k0 = kt * 32 + (l >> 4) * 8;
    int c = nf * 16 + (l & 15);
    f16x8 o;
#pragma unroll
    for (int j = 0; j < 8; ++j) o[j] = (f16)W[(size_t)(k0 + j) * D_HID + c];
    *(f16x8*)(Wp + (size_t)u * 8) = o;
}

__global__ void k_pack_w2(const float* __restrict__ W, f16* __restrict__ Wp) {
    int u = blockIdx.x * blockDim.x + threadIdx.x;
    if (u >= 8 * 3 * 64) return;
    int l = u & 63;
    int nf = (u / 64) % 3;
    int kt = u / 192;
    int k0 = kt * 32 + (l >> 4) * 8;
    int c = nf * 16 + (l & 15);
    f16x8 o;
#pragma unroll
    for (int j = 0; j < 8; ++j)
        o[j] = (c < D_OUT) ? (f16)W[(size_t)(k0 + j) * D_OUT + c] : (f16)0.0f;
    *(f16x8*)(Wp + (size_t)u * 8) = o;
}

// ---------------- GEMM1: h1 = f16(x) @ W1, fused conversion ----------------
// block = 4 waves, 64 rows x 256 cols; wave = 64 rows x 64 cols.

__global__ __launch_bounds__(256) void k_gemm1(const float* __restrict__ X,
                                               const f16* __restrict__ Bp,
                                               f16* __restrict__ C) {
    int wid = threadIdx.x >> 6;
    int lane = threadIdx.x & 63;
    int rowBase = blockIdx.x * 64;
    int nf0 = wid * 4;
    int r_ = lane & 15, q_ = lane >> 4;

    f32x4 acc[4][4];
#pragma unroll
    for (int mi = 0; mi < 4; ++mi)
#pragma unroll
        for (int ni = 0; ni < 4; ++ni) acc[mi][ni] = (f32x4)(0.0f);

    for (int kt = 0; kt < 16; ++kt) {
        int k0 = kt * 32 + q_ * 8;
        f16x8 a[4], b[4];
#pragma unroll
        for (int mi = 0; mi < 4; ++mi) {
            const float4* p = (const float4*)(X + (size_t)(rowBase + mi * 16 + r_) * D_IN + k0);
            float4 lo = p[0], hi = p[1];
            f16x8 t;
            t[0] = (f16)lo.x; t[1] = (f16)lo.y; t[2] = (f16)lo.z; t[3] = (f16)lo.w;
            t[4] = (f16)hi.x; t[5] = (f16)hi.y; t[6] = (f16)hi.z; t[7] = (f16)hi.w;
            a[mi] = t;
        }
#pragma unroll
        for (int ni = 0; ni < 4; ++ni)
            b[ni] = *(const f16x8*)(Bp + ((size_t)(kt * 16 + nf0 + ni) * 64 + lane) * 8);
#pragma unroll
        for (int mi = 0; mi < 4; ++mi)
#pragma unroll
            for (int ni = 0; ni < 4; ++ni)
                acc[mi][ni] = __builtin_amdgcn_mfma_f32_16x16x32_f16(a[mi], b[ni], acc[mi][ni], 0, 0, 0);
    }

    int r0 = (lane >> 4) * 4;
    int c0 = lane & 15;
#pragma unroll
    for (int mi = 0; mi < 4; ++mi)
#pragma unroll
        for (int ni = 0; ni < 4; ++ni)
#pragma unroll
            for (int r = 0; r < 4; ++r) {
                int row = rowBase + mi * 16 + r0 + r;
                C[(size_t)row * D_HID + (nf0 + ni) * 16 + c0] = (f16)acc[mi][ni][r];
            }
}

// ---------------- GEMM2 (packed A, LDS-free) ----------------
// KT=8, NFB=3, WNF=3, 4 waves stacked on rows; block = 256r x 48c.
// grid 157: 157*4*64 = 40192 rows >= 40000 (tail waves return).

__global__ __launch_bounds__(256) void k_gemm2(const f16* __restrict__ Ap,
                                               const f16* __restrict__ Bp,
                                               f16* __restrict__ C) {
    int wid = threadIdx.x >> 6;
    int lane = threadIdx.x & 63;
    int rowTile = blockIdx.x * 4 + wid;
    int rowBase = rowTile * 64;
    if (rowBase >= N_NODES) return;

    f32x4 acc[4][3];
#pragma unroll
    for (int mi = 0; mi < 4; ++mi)
#pragma unroll
        for (int ni = 0; ni < 3; ++ni) acc[mi][ni] = (f32x4)(0.0f);

    int m16b = rowTile * 4;
    for (int kt = 0; kt < 8; ++kt) {
        f16x8 a[4], b[3];
#pragma unroll
        for (int mi = 0; mi < 4; ++mi)
            a[mi] = *(const f16x8*)(Ap + ((size_t)((m16b + mi) * 8 + kt) * 64 + lane) * 8);
#pragma unroll
        for (int ni = 0; ni < 3; ++ni)
            b[ni] = *(const f16x8*)(Bp + ((size_t)(kt * 3 + ni) * 64 + lane) * 8);
#pragma unroll
        for (int mi = 0; mi < 4; ++mi)
#pragma unroll
            for (int ni = 0; ni < 3; ++ni)
                acc[mi][ni] = __builtin_amdgcn_mfma_f32_16x16x32_f16(a[mi], b[ni], acc[mi][ni], 0, 0, 0);
    }

    int r0 = (lane >> 4) * 4;
    int c0 = lane & 15;
#pragma unroll
    for (int mi = 0; mi < 4; ++mi)
#pragma unroll
        for (int ni = 0; ni < 3; ++ni)
#pragma unroll
            for (int r = 0; r < 4; ++r) {
                int row = rowBase + mi * 16 + r0 + r;
                C[(size_t)row * D_OUT_PAD + ni * 16 + c0] = (f16)acc[mi][ni][r];
            }
}

// ---------------- aggregation 1: hp = packA(relu(Ahat*h1 + b1)) -----------
// Wave per node. Phase 1: preload <=64 edge (idx, weight) into lane regs.
// Phase 2: half-wave split (32 lanes x f16x8 = full 256-dim row), halves
// take alternate edges, unroll 2 -> 4 independent 512B gathers in flight.
// Output written directly in GEMM2 A-fragment packed order.

__global__ __launch_bounds__(256) void k_agg1(const f16* __restrict__ h1,
                                              const int* __restrict__ rowptr,
                                              const int* __restrict__ col,
                                              const float* __restrict__ dinv,
                                              const float* __restrict__ b1,
                                              f16* __restrict__ hp) {
    int node = blockIdx.x * 4 + (threadIdx.x >> 6);
    int lane = threadIdx.x & 63;
    int half = lane >> 5;
    int hl = lane & 31;
    float di = dinv[node];

    // issue self-row load early
    f16x8 selfv = *(const f16x8*)(h1 + (size_t)node * D_HID + hl * 8);

    float a[8];
#pragma unroll
    for (int j = 0; j < 8; ++j) a[j] = 0.0f;

    int e0 = rowptr[node], e1 = rowptr[node + 1];
    for (int base = e0; base < e1; base += 64) {
        int nn = min(64, e1 - base);
        int sidx = 0; float wv = 0.0f;
        if (lane < nn) {
            int s = col[base + lane];
            sidx = s;
            wv = dinv[s] * di;
        }
        int t = half;
        for (; t + 2 < nn; t += 4) {
            int s0 = __shfl(sidx, t), s1 = __shfl(sidx, t + 2);
            float w0 = __shfl(wv, t), w1 = __shfl(wv, t + 2);
            f16x8 u0 = *(const f16x8*)(h1 + (size_t)s0 * D_HID + hl * 8);
            f16x8 u1 = *(const f16x8*)(h1 + (size_t)s1 * D_HID + hl * 8);
#pragma unroll
            for (int j = 0; j < 8; ++j)
                a[j] += (float)u0[j] * w0 + (float)u1[j] * w1;
        }
        if (t < nn) {
            int s0 = __shfl(sidx, t);
            float w0 = __shfl(wv, t);
            f16x8 u0 = *(const f16x8*)(h1 + (size_t)s0 * D_HID + hl * 8);
#pragma unroll
            for (int j = 0; j < 8; ++j) a[j] += (float)u0[j] * w0;
        }
    }

    // combine halves (both end up with the total)
#pragma unroll
    for (int j = 0; j < 8; ++j) a[j] += __shfl_xor(a[j], 32);

    float wself = di * di;
    float4 b_lo = *(const float4*)(b1 + hl * 8);
    float4 b_hi = *(const float4*)(b1 + hl * 8 + 4);
    f16x8 o;
    o[0] = (f16)fmaxf(a[0] + (float)selfv[0] * wself + b_lo.x, 0.0f);
    o[1] = (f16)fmaxf(a[1] + (float)selfv[1] * wself + b_lo.y, 0.0f);
    o[2] = (f16)fmaxf(a[2] + (float)selfv[2] * wself + b_lo.z, 0.0f);
    o[3] = (f16)fmaxf(a[3] + (float)selfv[3] * wself + b_lo.w, 0.0f);
    o[4] = (f16)fmaxf(a[4] + (float)selfv[4] * wself + b_hi.x, 0.0f);
    o[5] = (f16)fmaxf(a[5] + (float)selfv[5] * wself + b_hi.y, 0.0f);
    o[6] = (f16)fmaxf(a[6] + (float)selfv[6] * wself + b_hi.z, 0.0f);
    o[7] = (f16)fmaxf(a[7] + (float)selfv[7] * wself + b_hi.w, 0.0f);

    if (half == 0) {
        // packed A (KT=8): dim d = hl*8+j ; kt = hl>>2 ; q = hl&3
        size_t idx = ((size_t)(node >> 4) * 8 + (hl >> 2)) * 512 + (hl & 3) * 128 + (node & 15) * 8;
        *(f16x8*)(hp + idx) = o;
    }
}

// ---------------- aggregation 2: out = log_softmax(Ahat*g + b2) -----------

__global__ __launch_bounds__(256) void k_agg2(const f16* __restrict__ g,
                                              const int* __restrict__ rowptr,
                                              const int* __restrict__ col,
                                              const float* __restrict__ dinv,
                                              const float* __restrict__ b2,
                                              float* __restrict__ out) {
    int node = blockIdx.x * 4 + (threadIdx.x >> 6);
    int lane = threadIdx.x & 63;
    float di = dinv[node];
    bool act = lane < D_OUT_PAD;
    float acc = act ? (float)g[(size_t)node * D_OUT_PAD + lane] * di * di : 0.0f;

    int e0 = rowptr[node], e1 = rowptr[node + 1];
    for (int base = e0; base < e1; base += 64) {
        int nn = min(64, e1 - base);
        int sidx = 0; float wv = 0.0f;
        if (lane < nn) {
            int s = col[base + lane];
            sidx = s;
            wv = dinv[s] * di;
        }
        int k = 0;
        for (; k + 4 <= nn; k += 4) {
            int s0 = __shfl(sidx, k), s1 = __shfl(sidx, k + 1);
            int s2 = __shfl(sidx, k + 2), s3 = __shfl(sidx, k + 3);
            float w0 = __shfl(wv, k), w1 = __shfl(wv, k + 1);
            float w2 = __shfl(wv, k + 2), w3 = __shfl(wv, k + 3);
            if (act) {
                float u0 = (float)g[(size_t)s0 * D_OUT_PAD + lane];
                float u1 = (float)g[(size_t)s1 * D_OUT_PAD + lane];
                float u2 = (float)g[(size_t)s2 * D_OUT_PAD + lane];
                float u3 = (float)g[(size_t)s3 * D_OUT_PAD + lane];
                acc += u0 * w0 + u1 * w1 + u2 * w2 + u3 * w3;
            }
        }
        for (; k < nn; ++k) {
            int s0 = __shfl(sidx, k);
            float w0 = __shfl(wv, k);
            if (act) acc += (float)g[(size_t)s0 * D_OUT_PAD + lane] * w0;
        }
    }

    float z = (lane < D_OUT) ? acc + b2[lane] : -3.0e38f;
    float mx = z;
#pragma unroll
    for (int off = 32; off >= 1; off >>= 1) mx = fmaxf(mx, __shfl_xor(mx, off));
    float ex = (lane < D_OUT) ? expf(z - mx) : 0.0f;
    float sum = ex;
#pragma unroll
    for (int off = 32; off >= 1; off >>= 1) sum += __shfl_xor(sum, off);
    if (lane < D_OUT) out[(size_t)node * D_OUT + lane] = z - mx - logf(sum);
}

// ---------------- launcher ----------------

extern "C" void kernel_launch(void* const* d_in, const int* in_sizes, int n_in,
                              void* d_out, int out_size, void* d_ws, size_t ws_size,
                              hipStream_t stream) {
    const float* x  = (const float*)d_in[0];
    const int*   ei = (const int*)d_in[1];
    const float* W1 = (const float*)d_in[2];
    const float* b1 = (const float*)d_in[3];
    const float* W2 = (const float*)d_in[4];
    const float* b2 = (const float*)d_in[5];
    float* out = (float*)d_out;

    char* ws = (char*)d_ws;
    int*   degi   = (int*)(ws + 0);              // 160,000
    int*   cursor = (int*)(ws + 160000);         // 160,000
    float* dinv   = (float*)(ws + 320000);       // 160,000
    int*   rowptr = (int*)(ws + 480000);         // 160,256 (40001 ints)
    int*   col    = (int*)(ws + 640256);         // 2,560,000
    f16*   w1p    = (f16*)(ws + 3200256);        // 262,144
    f16*   w2p    = (f16*)(ws + 3462400);        // 24,576
    f16*   h1     = (f16*)(ws + 3486976);        // 20,480,000
    f16*   hpk    = (f16*)(ws + 23966976);       // 20,480,000 (packed A, GEMM2)
    f16*   g      = (f16*)(ws + 44446976);       // 3,840,000
    // total 48,286,976 bytes

    hipMemsetAsync(d_ws, 0, 320000, stream);  // degi + cursor

    k_degree<<<2500, 256, 0, stream>>>(ei, degi);
    k_scan<<<1, 1024, 0, stream>>>(degi, rowptr, dinv);
    k_fill<<<2500, 256, 0, stream>>>(ei, rowptr, cursor, col);

    k_pack_w1<<<64, 256, 0, stream>>>(W1, w1p);
    k_pack_w2<<<6, 256, 0, stream>>>(W2, w2p);

    k_gemm1<<<625, 256, 0, stream>>>(x, w1p, h1);
    k_agg1<<<10000, 256, 0, stream>>>(h1, rowptr, col, dinv, b1, hpk);
    k_gemm2<<<157, 256, 0, stream>>>(hpk, w2p, g);
    k_agg2<<<10000, 256, 0, stream>>>(g, rowptr, col, dinv, b2, out);
}

// Round 5
// 221.844 us; speedup vs baseline: 1.5560x; 1.0136x over previous
//
#include <hip/hip_runtime.h>

// ---------------------------------------------------------------------------
// GCN 2-layer forward on MI355X.
//   memset(deg,cursor)=0
//   k_degree: deg[dst]++                         (int atomics)
//   k_scan:   rowptr = exscan(deg) + dinv=rsqrt(deg+1)   (parallel, 1 block)
//   k_fill:   col[rowptr[dst]+pos++] = src       (CSR by dst)
//   k_pack_w1/w2: W -> MFMA B-fragment f16 (W2 padded to 48)
//   k_gemm1:  h1 = f16(x) @ W1   (fused cvt, 32rx64c waves, dbuf prefetch)
//   k_agg1:   hp = packA(relu(Ahat*h1 + b1))     (MLP gather + fused pack)
//   k_gemm2:  g = hp @ W2  (48 cols, col47 zero)
//   k_agg2:   out = log_softmax(Ahat*g + b2)
// ---------------------------------------------------------------------------

typedef _Float16 f16;
typedef _Float16 f16x8 __attribute__((ext_vector_type(8)));
typedef float f32x4 __attribute__((ext_vector_type(4)));

#define N_NODES 40000
#define N_EDGES 640000
#define D_IN 512
#define D_HID 256
#define D_OUT 47
#define D_OUT_PAD 48

// ---------------- CSR build ----------------

__global__ void k_degree(const int* __restrict__ eidx, int* __restrict__ deg) {
    int e = blockIdx.x * blockDim.x + threadIdx.x;
    if (e < N_EDGES) atomicAdd(&deg[eidx[N_EDGES + e]], 1);
}

// Parallel single-block scan: 1024 threads x 40 elems; fused dinv.
__global__ __launch_bounds__(1024) void k_scan(const int* __restrict__ deg,
                                               int* __restrict__ rowptr,
                                               float* __restrict__ dinv) {
    __shared__ int wsum[16];
    const int S = 40;
    int t = threadIdx.x;
    int lane = t & 63;
    int wid = t >> 6;
    int base = t * S;
    bool live = (base < N_NODES);

    int v[S];
    int tot = 0;
#pragma unroll
    for (int i = 0; i < S / 4; ++i) {
        int4 q = make_int4(0, 0, 0, 0);
        if (live) q = *(const int4*)(deg + base + i * 4);
        v[i * 4 + 0] = q.x; v[i * 4 + 1] = q.y;
        v[i * 4 + 2] = q.z; v[i * 4 + 3] = q.w;
        tot += q.x + q.y + q.z + q.w;
    }
    int inc = tot;
#pragma unroll
    for (int off = 1; off < 64; off <<= 1) {
        int n = __shfl_up(inc, off);
        if (lane >= off) inc += n;
    }
    if (lane == 63) wsum[wid] = inc;
    __syncthreads();
    if (t < 16) {
        int wv = wsum[t];
        int winc = wv;
#pragma unroll
        for (int off = 1; off < 16; off <<= 1) {
            int n = __shfl_up(winc, off);
            if (t >= off) winc += n;
        }
        wsum[t] = winc - wv;
    }
    __syncthreads();
    int acc = wsum[wid] + (inc - tot);
#pragma unroll
    for (int i = 0; i < S / 4; ++i) {
        int4 r; float4 f;
        r.x = acc; f.x = rsqrtf((float)(v[i * 4 + 0] + 1)); acc += v[i * 4 + 0];
        r.y = acc; f.y = rsqrtf((float)(v[i * 4 + 1] + 1)); acc += v[i * 4 + 1];
        r.z = acc; f.z = rsqrtf((float)(v[i * 4 + 2] + 1)); acc += v[i * 4 + 2];
        r.w = acc; f.w = rsqrtf((float)(v[i * 4 + 3] + 1)); acc += v[i * 4 + 3];
        if (live) {
            *(int4*)(rowptr + base + i * 4) = r;
            *(float4*)(dinv + base + i * 4) = f;
        }
    }
    if (t == 0) rowptr[N_NODES] = N_EDGES;
}

__global__ void k_fill(const int* __restrict__ eidx, const int* __restrict__ rowptr,
                       int* __restrict__ cursor, int* __restrict__ col) {
    int e = blockIdx.x * blockDim.x + threadIdx.x;
    if (e < N_EDGES) {
        int s = eidx[e];
        int d = eidx[N_EDGES + e];
        int pos = atomicAdd(&cursor[d], 1);
        col[rowptr[d] + pos] = s;
    }
}

// ---------------- weight packing (B-fragment order) ----------------
// lane l holds B[k = kt*32 + (l>>4)*8 + j][col = nf*16 + (l&15)]
// packed at ((kt*NFB + nf)*64 + l)*8 + j

__global__ void k_pack_w1(const float* __restrict__ W, f16* __restrict__ Wp) {
    int u = blockIdx.x * blockDim.x + threadIdx.x;
    if (u >= 16 * 16 * 64) return;
    int l = u & 63;
    int nf = (u >> 6) & 15;
    int kt = u >> 10;
    int k0 = kt * 32 + (l >> 4) * 8;
    int c = nf * 16 + (l & 15);
    f16x8 o;
#pragma unroll
    for (int j = 0; j < 8; ++j) o[j] = (f16)W[(size_t)(k0 + j) * D_HID + c];
    *(f16x8*)(Wp + (size_t)u * 8) = o;
}

__global__ void k_pack_w2(const float* __restrict__ W, f16* __restrict__ Wp) {
    int u = blockIdx.x * blockDim.x + threadIdx.x;
    if (u >= 8 * 3 * 64) return;
    int l = u & 63;
    int nf = (u / 64) % 3;
    int kt = u / 192;
    int k0 = kt * 32 + (l >> 4) * 8;
    int c = nf * 16 + (l & 15);
    f16x8 o;
#pragma unroll
    for (int j = 0; j < 8; ++j)
        o[j] = (c < D_OUT) ? (f16)W[(size_t)(k0 + j) * D_OUT + c] : (f16)0.0f;
    *(f16x8*)(Wp + (size_t)u * 8) = o;
}

// ---------------- GEMM1: h1 = f16(x) @ W1, fused conversion ----------------
// 1250 blocks x 4 waves; wave = 32 rows x 64 cols (5000 waves -> ~5/SIMD).
// Explicit double-buffered register prefetch (one kt ahead).

#define G1_LOADA(areg, kt_)                                                  \
    {                                                                        \
        int k0 = (kt_) * 32 + q_ * 8;                                        \
        const float4* p0 = (const float4*)(xrow0 + k0);                      \
        const float4* p1 = (const float4*)(xrow1 + k0);                      \
        float4 lo0 = p0[0], hi0 = p0[1], lo1 = p1[0], hi1 = p1[1];           \
        f16x8 t0, t1;                                                        \
        t0[0] = (f16)lo0.x; t0[1] = (f16)lo0.y; t0[2] = (f16)lo0.z;          \
        t0[3] = (f16)lo0.w; t0[4] = (f16)hi0.x; t0[5] = (f16)hi0.y;          \
        t0[6] = (f16)hi0.z; t0[7] = (f16)hi0.w;                              \
        t1[0] = (f16)lo1.x; t1[1] = (f16)lo1.y; t1[2] = (f16)lo1.z;          \
        t1[3] = (f16)lo1.w; t1[4] = (f16)hi1.x; t1[5] = (f16)hi1.y;          \
        t1[6] = (f16)hi1.z; t1[7] = (f16)hi1.w;                              \
        areg##0 = t0; areg##1 = t1;                                          \
    }

#define G1_LOADB(breg, kt_)                                                  \
    {                                                                        \
        const f16* bp = Bp + ((size_t)((kt_) * 16 + nf0) * 64 + lane) * 8;   \
        breg##0 = *(const f16x8*)(bp);                                       \
        breg##1 = *(const f16x8*)(bp + 512);                                 \
        breg##2 = *(const f16x8*)(bp + 1024);                                \
        breg##3 = *(const f16x8*)(bp + 1536);                                \
    }

#define G1_MFMA(areg, breg)                                                  \
    acc00 = __builtin_amdgcn_mfma_f32_16x16x32_f16(areg##0, breg##0, acc00, 0, 0, 0); \
    acc01 = __builtin_amdgcn_mfma_f32_16x16x32_f16(areg##0, breg##1, acc01, 0, 0, 0); \
    acc02 = __builtin_amdgcn_mfma_f32_16x16x32_f16(areg##0, breg##2, acc02, 0, 0, 0); \
    acc03 = __builtin_amdgcn_mfma_f32_16x16x32_f16(areg##0, breg##3, acc03, 0, 0, 0); \
    acc10 = __builtin_amdgcn_mfma_f32_16x16x32_f16(areg##1, breg##0, acc10, 0, 0, 0); \
    acc11 = __builtin_amdgcn_mfma_f32_16x16x32_f16(areg##1, breg##1, acc11, 0, 0, 0); \
    acc12 = __builtin_amdgcn_mfma_f32_16x16x32_f16(areg##1, breg##2, acc12, 0, 0, 0); \
    acc13 = __builtin_amdgcn_mfma_f32_16x16x32_f16(areg##1, breg##3, acc13, 0, 0, 0);

__global__ __launch_bounds__(256) void k_gemm1(const float* __restrict__ X,
                                               const f16* __restrict__ Bp,
                                               f16* __restrict__ C) {
    int wid = threadIdx.x >> 6;
    int lane = threadIdx.x & 63;
    int rb = blockIdx.x >> 1;                    // 0..624 (64-row slab)
    int cb = blockIdx.x & 1;                     // 0..1   (128-col slab)
    int rowBase = rb * 64 + (wid >> 1) * 32;     // 32 rows per wave
    int nf0 = cb * 8 + (wid & 1) * 4;            // 4x16 cols per wave
    int r_ = lane & 15, q_ = lane >> 4;

    const float* xrow0 = X + (size_t)(rowBase + r_) * D_IN;
    const float* xrow1 = X + (size_t)(rowBase + 16 + r_) * D_IN;

    f32x4 acc00 = (f32x4)(0.0f), acc01 = (f32x4)(0.0f), acc02 = (f32x4)(0.0f), acc03 = (f32x4)(0.0f);
    f32x4 acc10 = (f32x4)(0.0f), acc11 = (f32x4)(0.0f), acc12 = (f32x4)(0.0f), acc13 = (f32x4)(0.0f);

    f16x8 pA0, pA1, pB0, pB1, pB2, pB3;   // ping
    f16x8 qA0, qA1, qB0, qB1, qB2, qB3;   // pong

    G1_LOADA(pA, 0)
    G1_LOADB(pB, 0)
#pragma unroll
    for (int kt = 0; kt < 16; kt += 2) {
        G1_LOADA(qA, kt + 1)
        G1_LOADB(qB, kt + 1)
        G1_MFMA(pA, pB)
        if (kt + 2 < 16) {
            G1_LOADA(pA, kt + 2)
            G1_LOADB(pB, kt + 2)
        }
        G1_MFMA(qA, qB)
    }

    int r0 = (lane >> 4) * 4;
    int c0 = lane & 15;
    f32x4 accs[2][4] = {{acc00, acc01, acc02, acc03}, {acc10, acc11, acc12, acc13}};
#pragma unroll
    for (int mi = 0; mi < 2; ++mi)
#pragma unroll
        for (int ni = 0; ni < 4; ++ni)
#pragma unroll
            for (int r = 0; r < 4; ++r) {
                int row = rowBase + mi * 16 + r0 + r;
                C[(size_t)row * D_HID + (nf0 + ni) * 16 + c0] = (f16)accs[mi][ni][r];
            }
}

// ---------------- GEMM2 (packed A, LDS-free) ----------------
// KT=8, NFB=3, WNF=3, 4 waves stacked on rows; block = 256r x 48c.
// grid 157: 157*4*64 = 40192 rows >= 40000 (tail waves return).

__global__ __launch_bounds__(256) void k_gemm2(const f16* __restrict__ Ap,
                                               const f16* __restrict__ Bp,
                                               f16* __restrict__ C) {
    int wid = threadIdx.x >> 6;
    int lane = threadIdx.x & 63;
    int rowTile = blockIdx.x * 4 + wid;
    int rowBase = rowTile * 64;
    if (rowBase >= N_NODES) return;

    f32x4 acc[4][3];
#pragma unroll
    for (int mi = 0; mi < 4; ++mi)
#pragma unroll
        for (int ni = 0; ni < 3; ++ni) acc[mi][ni] = (f32x4)(0.0f);

    int m16b = rowTile * 4;
    for (int kt = 0; kt < 8; ++kt) {
        f16x8 a[4], b[3];
#pragma unroll
        for (int mi = 0; mi < 4; ++mi)
            a[mi] = *(const f16x8*)(Ap + ((size_t)((m16b + mi) * 8 + kt) * 64 + lane) * 8);
#pragma unroll
        for (int ni = 0; ni < 3; ++ni)
            b[ni] = *(const f16x8*)(Bp + ((size_t)(kt * 3 + ni) * 64 + lane) * 8);
#pragma unroll
        for (int mi = 0; mi < 4; ++mi)
#pragma unroll
            for (int ni = 0; ni < 3; ++ni)
                acc[mi][ni] = __builtin_amdgcn_mfma_f32_16x16x32_f16(a[mi], b[ni], acc[mi][ni], 0, 0, 0);
    }

    int r0 = (lane >> 4) * 4;
    int c0 = lane & 15;
#pragma unroll
    for (int mi = 0; mi < 4; ++mi)
#pragma unroll
        for (int ni = 0; ni < 3; ++ni)
#pragma unroll
            for (int r = 0; r < 4; ++r) {
                int row = rowBase + mi * 16 + r0 + r;
                C[(size_t)row * D_OUT_PAD + ni * 16 + c0] = (f16)acc[mi][ni][r];
            }
}

// ---------------- aggregation 1: hp = packA(relu(Ahat*h1 + b1)) -----------

__global__ __launch_bounds__(256) void k_agg1(const f16* __restrict__ h1,
                                              const int* __restrict__ rowptr,
                                              const int* __restrict__ col,
                                              const float* __restrict__ dinv,
                                              const float* __restrict__ b1,
                                              f16* __restrict__ hp) {
    int node = blockIdx.x * 4 + (threadIdx.x >> 6);
    int lane = threadIdx.x & 63;
    int half = lane >> 5;
    int hl = lane & 31;
    float di = dinv[node];

    f16x8 selfv = *(const f16x8*)(h1 + (size_t)node * D_HID + hl * 8);

    float a[8];
#pragma unroll
    for (int j = 0; j < 8; ++j) a[j] = 0.0f;

    int e0 = rowptr[node], e1 = rowptr[node + 1];
    for (int base = e0; base < e1; base += 64) {
        int nn = min(64, e1 - base);
        int sidx = 0; float wv = 0.0f;
        if (lane < nn) {
            int s = col[base + lane];
            sidx = s;
            wv = dinv[s] * di;
        }
        int t = half;
        for (; t + 2 < nn; t += 4) {
            int s0 = __shfl(sidx, t), s1 = __shfl(sidx, t + 2);
            float w0 = __shfl(wv, t), w1 = __shfl(wv, t + 2);
            f16x8 u0 = *(const f16x8*)(h1 + (size_t)s0 * D_HID + hl * 8);
            f16x8 u1 = *(const f16x8*)(h1 + (size_t)s1 * D_HID + hl * 8);
#pragma unroll
            for (int j = 0; j < 8; ++j)
                a[j] += (float)u0[j] * w0 + (float)u1[j] * w1;
        }
        if (t < nn) {
            int s0 = __shfl(sidx, t);
            float w0 = __shfl(wv, t);
            f16x8 u0 = *(const f16x8*)(h1 + (size_t)s0 * D_HID + hl * 8);
#pragma unroll
            for (int j = 0; j < 8; ++j) a[j] += (float)u0[j] * w0;
        }
    }

#pragma unroll
    for (int j = 0; j < 8; ++j) a[j] += __shfl_xor(a[j], 32);

    float wself = di * di;
    float4 b_lo = *(const float4*)(b1 + hl * 8);
    float4 b_hi = *(const float4*)(b1 + hl * 8 + 4);
    f16x8 o;
    o[0] = (f16)fmaxf(a[0] + (float)selfv[0] * wself + b_lo.x, 0.0f);
    o[1] = (f16)fmaxf(a[1] + (float)selfv[1] * wself + b_lo.y, 0.0f);
    o[2] = (f16)fmaxf(a[2] + (float)selfv[2] * wself + b_lo.z, 0.0f);
    o[3] = (f16)fmaxf(a[3] + (float)selfv[3] * wself + b_lo.w, 0.0f);
    o[4] = (f16)fmaxf(a[4] + (float)selfv[4] * wself + b_hi.x, 0.0f);
    o[5] = (f16)fmaxf(a[5] + (float)selfv[5] * wself + b_hi.y, 0.0f);
    o[6] = (f16)fmaxf(a[6] + (float)selfv[6] * wself + b_hi.z, 0.0f);
    o[7] = (f16)fmaxf(a[7] + (float)selfv[7] * wself + b_hi.w, 0.0f);

    if (half == 0) {
        size_t idx = ((size_t)(node >> 4) * 8 + (hl >> 2)) * 512 + (hl & 3) * 128 + (node & 15) * 8;
        *(f16x8*)(hp + idx) = o;
    }
}

// ---------------- aggregation 2: out = log_softmax(Ahat*g + b2) -----------

__global__ __launch_bounds__(256) void k_agg2(const f16* __restrict__ g,
                                              const int* __restrict__ rowptr,
                                              const int* __restrict__ col,
                                              const float* __restrict__ dinv,
                                              const float* __restrict__ b2,
                                              float* __restrict__ out) {
    int node = blockIdx.x * 4 + (threadIdx.x >> 6);
    int lane = threadIdx.x & 63;
    float di = dinv[node];
    bool act = lane < D_OUT_PAD;
    float acc = act ? (float)g[(size_t)node * D_OUT_PAD + lane] * di * di : 0.0f;

    int e0 = rowptr[node], e1 = rowptr[node + 1];
    for (int base = e0; base < e1; base += 64) {
        int nn = min(64, e1 - base);
        int sidx = 0; float wv = 0.0f;
        if (lane < nn) {
            int s = col[base + lane];
            sidx = s;
            wv = dinv[s] * di;
        }
        int k = 0;
        for (; k + 4 <= nn; k += 4) {
            int s0 = __shfl(sidx, k), s1 = __shfl(sidx, k + 1);
            int s2 = __shfl(sidx, k + 2), s3 = __shfl(sidx, k + 3);
            float w0 = __shfl(wv, k), w1 = __shfl(wv, k + 1);
            float w2 = __shfl(wv, k + 2), w3 = __shfl(wv, k + 3);
            if (act) {
                float u0 = (float)g[(size_t)s0 * D_OUT_PAD + lane];
                float u1 = (float)g[(size_t)s1 * D_OUT_PAD + lane];
                float u2 = (float)g[(size_t)s2 * D_OUT_PAD + lane];
                float u3 = (float)g[(size_t)s3 * D_OUT_PAD + lane];
                acc += u0 * w0 + u1 * w1 + u2 * w2 + u3 * w3;
            }
        }
        for (; k < nn; ++k) {
            int s0 = __shfl(sidx, k);
            float w0 = __shfl(wv, k);
            if (act) acc += (float)g[(size_t)s0 * D_OUT_PAD + lane] * w0;
        }
    }

    float z = (lane < D_OUT) ? acc + b2[lane] : -3.0e38f;
    float mx = z;
#pragma unroll
    for (int off = 32; off >= 1; off >>= 1) mx = fmaxf(mx, __shfl_xor(mx, off));
    float ex = (lane < D_OUT) ? expf(z - mx) : 0.0f;
    float sum = ex;
#pragma unroll
    for (int off = 32; off >= 1; off >>= 1) sum += __shfl_xor(sum, off);
    if (lane < D_OUT) out[(size_t)node * D_OUT + lane] = z - mx - logf(sum);
}

// ---------------- launcher ----------------

extern "C" void kernel_launch(void* const* d_in, const int* in_sizes, int n_in,
                              void* d_out, int out_size, void* d_ws, size_t ws_size,
                              hipStream_t stream) {
    const float* x  = (const float*)d_in[0];
    const int*   ei = (const int*)d_in[1];
    const float* W1 = (const float*)d_in[2];
    const float* b1 = (const float*)d_in[3];
    const float* W2 = (const float*)d_in[4];
    const float* b2 = (const float*)d_in[5];
    float* out = (float*)d_out;

    char* ws = (char*)d_ws;
    int*   degi   = (int*)(ws + 0);              // 160,000
    int*   cursor = (int*)(ws + 160000);         // 160,000
    float* dinv   = (float*)(ws + 320000);       // 160,000
    int*   rowptr = (int*)(ws + 480000);         // 160,256 (40001 ints)
    int*   col    = (int*)(ws + 640256);         // 2,560,000
    f16*   w1p    = (f16*)(ws + 3200256);        // 262,144
    f16*   w2p    = (f16*)(ws + 3462400);        // 24,576
    f16*   h1     = (f16*)(ws + 3486976);        // 20,480,000
    f16*   hpk    = (f16*)(ws + 23966976);       // 20,480,000 (packed A, GEMM2)
    f16*   g      = (f16*)(ws + 44446976);       // 3,840,000
    // total 48,286,976 bytes

    hipMemsetAsync(d_ws, 0, 320000, stream);  // degi + cursor

    k_degree<<<2500, 256, 0, stream>>>(ei, degi);
    k_scan<<<1, 1024, 0, stream>>>(degi, rowptr, dinv);
    k_fill<<<2500, 256, 0, stream>>>(ei, rowptr, cursor, col);

    k_pack_w1<<<64, 256, 0, stream>>>(W1, w1p);
    k_pack_w2<<<6, 256, 0, stream>>>(W2, w2p);

    k_gemm1<<<1250, 256, 0, stream>>>(x, w1p, h1);
    k_agg1<<<10000, 256, 0, stream>>>(h1, rowptr, col, dinv, b1, hpk);
    k_gemm2<<<157, 256, 0, stream>>>(hpk, w2p, g);
    k_agg2<<<10000, 256, 0, stream>>>(g, rowptr, col, dinv, b2, out);
}

// Round 6
// 198.953 us; speedup vs baseline: 1.7350x; 1.1151x over previous
//
#include <hip/hip_runtime.h>

// ---------------------------------------------------------------------------
// GCN 2-layer forward on MI355X.
//   memset(deg,cursor)=0
//   k_degree: deg[dst]++                         (int atomics)
//   k_scan:   rowptr = exscan(deg) + dinv=rsqrt(deg+1)   (parallel, 1 block)
//   k_fill:   col[rowptr[dst]+pos++] = src       (CSR by dst)
//   k_pack_w1/w2: W -> MFMA B-fragment f16 (W2 padded to 48)
//   k_gemm1:  h1 = f16(x) @ W1   (LDS-staged: coalesced full-row reads,
//             f32->f16 convert into padded LDS, ds_read_b128 fragments)
//   k_agg1:   hp = packA(relu(Ahat*h1 + b1))     (MLP gather + fused pack)
//   k_gemm2:  g = hp @ W2  (48 cols, col47 zero)
//   k_agg2:   out = log_softmax(Ahat*g + b2)
// ---------------------------------------------------------------------------

typedef _Float16 f16;
typedef _Float16 f16x8 __attribute__((ext_vector_type(8)));
typedef _Float16 f16x4 __attribute__((ext_vector_type(4)));
typedef float f32x4 __attribute__((ext_vector_type(4)));

#define N_NODES 40000
#define N_EDGES 640000
#define D_IN 512
#define D_HID 256
#define D_OUT 47
#define D_OUT_PAD 48

// ---------------- CSR build ----------------

__global__ void k_degree(const int* __restrict__ eidx, int* __restrict__ deg) {
    int e = blockIdx.x * blockDim.x + threadIdx.x;
    if (e < N_EDGES) atomicAdd(&deg[eidx[N_EDGES + e]], 1);
}

// Parallel single-block scan: 1024 threads x 40 elems; fused dinv.
__global__ __launch_bounds__(1024) void k_scan(const int* __restrict__ deg,
                                               int* __restrict__ rowptr,
                                               float* __restrict__ dinv) {
    __shared__ int wsum[16];
    const int S = 40;
    int t = threadIdx.x;
    int lane = t & 63;
    int wid = t >> 6;
    int base = t * S;
    bool live = (base < N_NODES);

    int v[S];
    int tot = 0;
#pragma unroll
    for (int i = 0; i < S / 4; ++i) {
        int4 q = make_int4(0, 0, 0, 0);
        if (live) q = *(const int4*)(deg + base + i * 4);
        v[i * 4 + 0] = q.x; v[i * 4 + 1] = q.y;
        v[i * 4 + 2] = q.z; v[i * 4 + 3] = q.w;
        tot += q.x + q.y + q.z + q.w;
    }
    int inc = tot;
#pragma unroll
    for (int off = 1; off < 64; off <<= 1) {
        int n = __shfl_up(inc, off);
        if (lane >= off) inc += n;
    }
    if (lane == 63) wsum[wid] = inc;
    __syncthreads();
    if (t < 16) {
        int wv = wsum[t];
        int winc = wv;
#pragma unroll
        for (int off = 1; off < 16; off <<= 1) {
            int n = __shfl_up(winc, off);
            if (t >= off) winc += n;
        }
        wsum[t] = winc - wv;
    }
    __syncthreads();
    int acc = wsum[wid] + (inc - tot);
#pragma unroll
    for (int i = 0; i < S / 4; ++i) {
        int4 r; float4 f;
        r.x = acc; f.x = rsqrtf((float)(v[i * 4 + 0] + 1)); acc += v[i * 4 + 0];
        r.y = acc; f.y = rsqrtf((float)(v[i * 4 + 1] + 1)); acc += v[i * 4 + 1];
        r.z = acc; f.z = rsqrtf((float)(v[i * 4 + 2] + 1)); acc += v[i * 4 + 2];
        r.w = acc; f.w = rsqrtf((float)(v[i * 4 + 3] + 1)); acc += v[i * 4 + 3];
        if (live) {
            *(int4*)(rowptr + base + i * 4) = r;
            *(float4*)(dinv + base + i * 4) = f;
        }
    }
    if (t == 0) rowptr[N_NODES] = N_EDGES;
}

__global__ void k_fill(const int* __restrict__ eidx, const int* __restrict__ rowptr,
                       int* __restrict__ cursor, int* __restrict__ col) {
    int e = blockIdx.x * blockDim.x + threadIdx.x;
    if (e < N_EDGES) {
        int s = eidx[e];
        int d = eidx[N_EDGES + e];
        int pos = atomicAdd(&cursor[d], 1);
        col[rowptr[d] + pos] = s;
    }
}

// ---------------- weight packing (B-fragment order) ----------------
// lane l holds B[k = kt*32 + (l>>4)*8 + j][col = nf*16 + (l&15)]
// packed at ((kt*NFB + nf)*64 + l)*8 + j

__global__ void k_pack_w1(const float* __restrict__ W, f16* __restrict__ Wp) {
    int u = blockIdx.x * blockDim.x + threadIdx.x;
    if (u >= 16 * 16 * 64) return;
    int l = u & 63;
    int nf = (u >> 6) & 15;
    int kt = u >> 10;
    int k0 = kt * 32 + (l >> 4) * 8;
    int c = nf * 16 + (l & 15);
    f16x8 o;
#pragma unroll
    for (int j = 0; j < 8; ++j) o[j] = (f16)W[(size_t)(k0 + j) * D_HID + c];
    *(f16x8*)(Wp + (size_t)u * 8) = o;
}

__global__ void k_pack_w2(const float* __restrict__ W, f16* __restrict__ Wp) {
    int u = blockIdx.x * blockDim.x + threadIdx.x;
    if (u >= 8 * 3 * 64) return;
    int l = u & 63;
    int nf = (u / 64) % 3;
    int kt = u / 192;
    int k0 = kt * 32 + (l >> 4) * 8;
    int c = nf * 16 + (l & 15);
    f16x8 o;
#pragma unroll
    for (int j = 0; j < 8; ++j)
        o[j] = (c < D_OUT) ? (f16)W[(size_t)(k0 + j) * D_OUT + c] : (f16)0.0f;
    *(f16x8*)(Wp + (size_t)u * 8) = o;
}

// ---------------- GEMM1: h1 = f16(x) @ W1, LDS-staged -------------------
// 625 blocks x 512 threads (8 waves). Block owns 64 rows x 256 cols.
// Stage: all 64 rows x 512 k as f16 into LDS[64][520] (pad 8 -> 2-way max
// bank aliasing on fragment reads). Staging reads are full contiguous rows:
// each wave instruction = 64 lanes x 16B = 1KB contiguous (zero scatter).
// Compute: wave = 64 rows x 32 cols; per kt: 4x ds_read_b128 (A) +
// 2x 16B global (B, L2-resident) + 8 MFMA.

__global__ __launch_bounds__(512) void k_gemm1(const float* __restrict__ X,
                                               const f16* __restrict__ Bp,
                                               f16* __restrict__ C) {
    __shared__ f16 As[64][520];
    int t = threadIdx.x;
    int lane = t & 63;
    int wid = t >> 6;
    int rowBase = blockIdx.x * 64;

    // ---- stage: 64 rows x 128 float4 = 8192 units, 16 iters x 512 thr ----
#pragma unroll
    for (int it = 0; it < 16; ++it) {
        int idx = it * 512 + t;
        int row = idx >> 7;        // 128 float4 per row
        int c4 = idx & 127;
        float4 v = *(const float4*)(X + (size_t)(rowBase + row) * D_IN + c4 * 4);
        f16x4 o;
        o[0] = (f16)v.x; o[1] = (f16)v.y; o[2] = (f16)v.z; o[3] = (f16)v.w;
        *(f16x4*)(&As[row][c4 * 4]) = o;
    }
    __syncthreads();

    // ---- compute ----
    int nf0 = wid * 2;             // 8 waves x 2 nf = 16 nf (256 cols)
    int r_ = lane & 15, q_ = lane >> 4;

    f32x4 acc[4][2];
#pragma unroll
    for (int mi = 0; mi < 4; ++mi)
#pragma unroll
        for (int ni = 0; ni < 2; ++ni) acc[mi][ni] = (f32x4)(0.0f);

#pragma unroll 4
    for (int kt = 0; kt < 16; ++kt) {
        f16x8 a[4], b[2];
#pragma unroll
        for (int mi = 0; mi < 4; ++mi)
            a[mi] = *(const f16x8*)(&As[mi * 16 + r_][kt * 32 + q_ * 8]);
#pragma unroll
        for (int ni = 0; ni < 2; ++ni)
            b[ni] = *(const f16x8*)(Bp + ((size_t)(kt * 16 + nf0 + ni) * 64 + lane) * 8);
#pragma unroll
        for (int mi = 0; mi < 4; ++mi)
#pragma unroll
            for (int ni = 0; ni < 2; ++ni)
                acc[mi][ni] = __builtin_amdgcn_mfma_f32_16x16x32_f16(a[mi], b[ni], acc[mi][ni], 0, 0, 0);
    }

    int r0 = q_ * 4;
    int c0 = r_;
#pragma unroll
    for (int mi = 0; mi < 4; ++mi)
#pragma unroll
        for (int ni = 0; ni < 2; ++ni)
#pragma unroll
            for (int r = 0; r < 4; ++r) {
                int row = rowBase + mi * 16 + r0 + r;
                C[(size_t)row * D_HID + (nf0 + ni) * 16 + c0] = (f16)acc[mi][ni][r];
            }
}

// ---------------- GEMM2 (packed A, LDS-free) ----------------
// KT=8, NFB=3, WNF=3, 4 waves stacked on rows; block = 256r x 48c.
// grid 157: 157*4*64 = 40192 rows >= 40000 (tail waves return).

__global__ __launch_bounds__(256) void k_gemm2(const f16* __restrict__ Ap,
                                               const f16* __restrict__ Bp,
                                               f16* __restrict__ C) {
    int wid = threadIdx.x >> 6;
    int lane = threadIdx.x & 63;
    int rowTile = blockIdx.x * 4 + wid;
    int rowBase = rowTile * 64;
    if (rowBase >= N_NODES) return;

    f32x4 acc[4][3];
#pragma unroll
    for (int mi = 0; mi < 4; ++mi)
#pragma unroll
        for (int ni = 0; ni < 3; ++ni) acc[mi][ni] = (f32x4)(0.0f);

    int m16b = rowTile * 4;
    for (int kt = 0; kt < 8; ++kt) {
        f16x8 a[4], b[3];
#pragma unroll
        for (int mi = 0; mi < 4; ++mi)
            a[mi] = *(const f16x8*)(Ap + ((size_t)((m16b + mi) * 8 + kt) * 64 + lane) * 8);
#pragma unroll
        for (int ni = 0; ni < 3; ++ni)
            b[ni] = *(const f16x8*)(Bp + ((size_t)(kt * 3 + ni) * 64 + lane) * 8);
#pragma unroll
        for (int mi = 0; mi < 4; ++mi)
#pragma unroll
            for (int ni = 0; ni < 3; ++ni)
                acc[mi][ni] = __builtin_amdgcn_mfma_f32_16x16x32_f16(a[mi], b[ni], acc[mi][ni], 0, 0, 0);
    }

    int r0 = (lane >> 4) * 4;
    int c0 = lane & 15;
#pragma unroll
    for (int mi = 0; mi < 4; ++mi)
#pragma unroll
        for (int ni = 0; ni < 3; ++ni)
#pragma unroll
            for (int r = 0; r < 4; ++r) {
                int row = rowBase + mi * 16 + r0 + r;
                C[(size_t)row * D_OUT_PAD + ni * 16 + c0] = (f16)acc[mi][ni][r];
            }
}

// ---------------- aggregation 1: hp = packA(relu(Ahat*h1 + b1)) -----------

__global__ __launch_bounds__(256) void k_agg1(const f16* __restrict__ h1,
                                              const int* __restrict__ rowptr,
                                              const int* __restrict__ col,
                                              const float* __restrict__ dinv,
                                              const float* __restrict__ b1,
                                              f16* __restrict__ hp) {
    int node = blockIdx.x * 4 + (threadIdx.x >> 6);
    int lane = threadIdx.x & 63;
    int half = lane >> 5;
    int hl = lane & 31;
    float di = dinv[node];

    f16x8 selfv = *(const f16x8*)(h1 + (size_t)node * D_HID + hl * 8);

    float a[8];
#pragma unroll
    for (int j = 0; j < 8; ++j) a[j] = 0.0f;

    int e0 = rowptr[node], e1 = rowptr[node + 1];
    for (int base = e0; base < e1; base += 64) {
        int nn = min(64, e1 - base);
        int sidx = 0; float wv = 0.0f;
        if (lane < nn) {
            int s = col[base + lane];
            sidx = s;
            wv = dinv[s] * di;
        }
        int t = half;
        for (; t + 2 < nn; t += 4) {
            int s0 = __shfl(sidx, t), s1 = __shfl(sidx, t + 2);
            float w0 = __shfl(wv, t), w1 = __shfl(wv, t + 2);
            f16x8 u0 = *(const f16x8*)(h1 + (size_t)s0 * D_HID + hl * 8);
            f16x8 u1 = *(const f16x8*)(h1 + (size_t)s1 * D_HID + hl * 8);
#pragma unroll
            for (int j = 0; j < 8; ++j)
                a[j] += (float)u0[j] * w0 + (float)u1[j] * w1;
        }
        if (t < nn) {
            int s0 = __shfl(sidx, t);
            float w0 = __shfl(wv, t);
            f16x8 u0 = *(const f16x8*)(h1 + (size_t)s0 * D_HID + hl * 8);
#pragma unroll
            for (int j = 0; j < 8; ++j) a[j] += (float)u0[j] * w0;
        }
    }

#pragma unroll
    for (int j = 0; j < 8; ++j) a[j] += __shfl_xor(a[j], 32);

    float wself = di * di;
    float4 b_lo = *(const float4*)(b1 + hl * 8);
    float4 b_hi = *(const float4*)(b1 + hl * 8 + 4);
    f16x8 o;
    o[0] = (f16)fmaxf(a[0] + (float)selfv[0] * wself + b_lo.x, 0.0f);
    o[1] = (f16)fmaxf(a[1] + (float)selfv[1] * wself + b_lo.y, 0.0f);
    o[2] = (f16)fmaxf(a[2] + (float)selfv[2] * wself + b_lo.z, 0.0f);
    o[3] = (f16)fmaxf(a[3] + (float)selfv[3] * wself + b_lo.w, 0.0f);
    o[4] = (f16)fmaxf(a[4] + (float)selfv[4] * wself + b_hi.x, 0.0f);
    o[5] = (f16)fmaxf(a[5] + (float)selfv[5] * wself + b_hi.y, 0.0f);
    o[6] = (f16)fmaxf(a[6] + (float)selfv[6] * wself + b_hi.z, 0.0f);
    o[7] = (f16)fmaxf(a[7] + (float)selfv[7] * wself + b_hi.w, 0.0f);

    if (half == 0) {
        size_t idx = ((size_t)(node >> 4) * 8 + (hl >> 2)) * 512 + (hl & 3) * 128 + (node & 15) * 8;
        *(f16x8*)(hp + idx) = o;
    }
}

// ---------------- aggregation 2: out = log_softmax(Ahat*g + b2) -----------

__global__ __launch_bounds__(256) void k_agg2(const f16* __restrict__ g,
                                              const int* __restrict__ rowptr,
                                              const int* __restrict__ col,
                                              const float* __restrict__ dinv,
                                              const float* __restrict__ b2,
                                              float* __restrict__ out) {
    int node = blockIdx.x * 4 + (threadIdx.x >> 6);
    int lane = threadIdx.x & 63;
    float di = dinv[node];
    bool act = lane < D_OUT_PAD;
    float acc = act ? (float)g[(size_t)node * D_OUT_PAD + lane] * di * di : 0.0f;

    int e0 = rowptr[node], e1 = rowptr[node + 1];
    for (int base = e0; base < e1; base += 64) {
        int nn = min(64, e1 - base);
        int sidx = 0; float wv = 0.0f;
        if (lane < nn) {
            int s = col[base + lane];
            sidx = s;
            wv = dinv[s] * di;
        }
        int k = 0;
        for (; k + 4 <= nn; k += 4) {
            int s0 = __shfl(sidx, k), s1 = __shfl(sidx, k + 1);
            int s2 = __shfl(sidx, k + 2), s3 = __shfl(sidx, k + 3);
            float w0 = __shfl(wv, k), w1 = __shfl(wv, k + 1);
            float w2 = __shfl(wv, k + 2), w3 = __shfl(wv, k + 3);
            if (act) {
                float u0 = (float)g[(size_t)s0 * D_OUT_PAD + lane];
                float u1 = (float)g[(size_t)s1 * D_OUT_PAD + lane];
                float u2 = (float)g[(size_t)s2 * D_OUT_PAD + lane];
                float u3 = (float)g[(size_t)s3 * D_OUT_PAD + lane];
                acc += u0 * w0 + u1 * w1 + u2 * w2 + u3 * w3;
            }
        }
        for (; k < nn; ++k) {
            int s0 = __shfl(sidx, k);
            float w0 = __shfl(wv, k);
            if (act) acc += (float)g[(size_t)s0 * D_OUT_PAD + lane] * w0;
        }
    }

    float z = (lane < D_OUT) ? acc + b2[lane] : -3.0e38f;
    float mx = z;
#pragma unroll
    for (int off = 32; off >= 1; off >>= 1) mx = fmaxf(mx, __shfl_xor(mx, off));
    float ex = (lane < D_OUT) ? expf(z - mx) : 0.0f;
    float sum = ex;
#pragma unroll
    for (int off = 32; off >= 1; off >>= 1) sum += __shfl_xor(sum, off);
    if (lane < D_OUT) out[(size_t)node * D_OUT + lane] = z - mx - logf(sum);
}

// ---------------- launcher ----------------

extern "C" void kernel_launch(void* const* d_in, const int* in_sizes, int n_in,
                              void* d_out, int out_size, void* d_ws, size_t ws_size,
                              hipStream_t stream) {
    const float* x  = (const float*)d_in[0];
    const int*   ei = (const int*)d_in[1];
    const float* W1 = (const float*)d_in[2];
    const float* b1 = (const float*)d_in[3];
    const float* W2 = (const float*)d_in[4];
    const float* b2 = (const float*)d_in[5];
    float* out = (float*)d_out;

    char* ws = (char*)d_ws;
    int*   degi   = (int*)(ws + 0);              // 160,000
    int*   cursor = (int*)(ws + 160000);         // 160,000
    float* dinv   = (float*)(ws + 320000);       // 160,000
    int*   rowptr = (int*)(ws + 480000);         // 160,256 (40001 ints)
    int*   col    = (int*)(ws + 640256);         // 2,560,000
    f16*   w1p    = (f16*)(ws + 3200256);        // 262,144
    f16*   w2p    = (f16*)(ws + 3462400);        // 24,576
    f16*   h1     = (f16*)(ws + 3486976);        // 20,480,000
    f16*   hpk    = (f16*)(ws + 23966976);       // 20,480,000 (packed A, GEMM2)
    f16*   g      = (f16*)(ws + 44446976);       // 3,840,000
    // total 48,286,976 bytes

    hipMemsetAsync(d_ws, 0, 320000, stream);  // degi + cursor

    k_degree<<<2500, 256, 0, stream>>>(ei, degi);
    k_scan<<<1, 1024, 0, stream>>>(degi, rowptr, dinv);
    k_fill<<<2500, 256, 0, stream>>>(ei, rowptr, cursor, col);

    k_pack_w1<<<64, 256, 0, stream>>>(W1, w1p);
    k_pack_w2<<<6, 256, 0, stream>>>(W2, w2p);

    k_gemm1<<<625, 512, 0, stream>>>(x, w1p, h1);
    k_agg1<<<10000, 256, 0, stream>>>(h1, rowptr, col, dinv, b1, hpk);
    k_gemm2<<<157, 256, 0, stream>>>(hpk, w2p, g);
    k_agg2<<<10000, 256, 0, stream>>>(g, rowptr, col, dinv, b2, out);
}